// Round 10
// baseline (408.083 us; speedup 1.0000x reference)
//
#include <hip/hip_runtime.h>

// AugmentedNeuralODE, round 10: restore 2 waves/SIMD to overlap the trans pipe.
// R8/R9 analysis: 1 wave/SIMD serializes ~128 quarter-rate trans wave-ops/eval
// (~1024 cyc, 52% of wall) with all full-rate/MFMA work. Fix: halve per-wave
// register state so 2 waves fit (<=256 regs incl AGPR): 2 waves share the same
// 16 samples, splitting out-tiles 4/4 AND L1 K-slabs 2/2.
//   wave w: L1 computes global slabs {2w,2w+1} (16 units/lane, W1=64 regs),
//   writes them to LDS, keeps them in regs; reads the other wave's 2 slabs
//   (2 ds_read_b128); MFMAs own-slabs-first so the reads hide behind 8 MFMAs.
//   W2 A-frags for tiles {4w..4w+3} = 64 AGPR + b2 16 AGPR (C-src init).
//   Epilogue: 8 h2 tanh-pairs + W3; shfl quad-reduce; float2 cross-wave
//   v-exchange via LDS. ~10 DS ops + 2 barriers/eval (vs R7's 28 -> DS pipe
//   stays under the compute wall). 1024 blocks x 128 thr = 8 waves/CU.
// Math: same tanh/bf16 path; only K-summation order differs for wave 1.

#define HID 128
#define TT  8
#define F(a,b) ((float)((double)(a)/(double)(b)))
#define K2C 2.8853900817779268f   // 2*log2(e), folded into W1/b1/W2/b2

typedef __attribute__((ext_vector_type(8))) short bf16x8;
typedef __attribute__((ext_vector_type(4))) float f32x4;
typedef __attribute__((ext_vector_type(2))) float f32x2;

union Frag { bf16x8 v; unsigned short u[8]; unsigned int d[4]; };

__device__ __forceinline__ f32x2 bc(float s) { return f32x2{s, s}; }
__device__ __forceinline__ f32x2 pk_fma(f32x2 a, f32x2 b, f32x2 c) {
#if __has_builtin(__builtin_elementwise_fma)
  return __builtin_elementwise_fma(a, b, c);
#else
  return a * b + c;
#endif
}
__device__ __forceinline__ float exp2_fast(float x) {
#if __has_builtin(__builtin_amdgcn_exp2f)
  return __builtin_amdgcn_exp2f(x);
#else
  return __builtin_exp2f(x);
#endif
}
__device__ __forceinline__ unsigned short f2bf(float f) {
  unsigned u = __builtin_bit_cast(unsigned, f);
  u += 0x7FFFu + ((u >> 16) & 1u);          // RNE
  return (unsigned short)(u >> 16);
}
__device__ __forceinline__ unsigned pack2bf(float a, float b) {
  unsigned ua = __builtin_bit_cast(unsigned, a);
  unsigned ub = __builtin_bit_cast(unsigned, b);
  ua += 0x7FFFu + ((ua >> 16) & 1u);
  ub += 0x7FFFu + ((ub >> 16) & 1u);
  return __builtin_amdgcn_perm(ub, ua, 0x07060302u);
}
// u pre-scaled by 2*log2(e): tanh(x) = 1 - 2/(exp2(u)+1)
__device__ __forceinline__ f32x2 tanh_pre(f32x2 u) {
  f32x2 e;
  e.x = exp2_fast(u.x);
  e.y = exp2_fast(u.y);
  f32x2 d = e + bc(1.0f);
  f32x2 r;
  r.x = __builtin_amdgcn_rcpf(d.x);
  r.y = __builtin_amdgcn_rcpf(d.y);
  return pk_fma(bc(-2.0f), r, bc(1.0f));
}

__global__ __launch_bounds__(128, 2) void node_kernel(
    const float* __restrict__ r0, const float* __restrict__ tarr,
    const float* __restrict__ W1, const float* __restrict__ b1,
    const float* __restrict__ W2, const float* __restrict__ b2,
    const float* __restrict__ W3, const float* __restrict__ b3,
    float* __restrict__ out)
{
  __shared__ uint4  h1X[16][16];   // [kk*4+quad][m16], 16B each; 4 KB
  __shared__ float2 vpX[2][16];    // per-wave partial velocity; 256 B

  const int tid  = (int)threadIdx.x;
  const int lane = tid & 63;
  const int w    = __builtin_amdgcn_readfirstlane(tid >> 6); // 0 or 1
  const int quad = lane >> 4;
  const int m16  = lane & 15;
  const int s    = (int)blockIdx.x * 16 + m16;
  const int ko   = (1 - w) * 2;        // other wave's first slab

  // ---- preloads, K2-folded ----
  // L1 coeffs for my 2 slabs: units i = (2w+so)*32 + quad*8 + j  (64 regs)
  f32x2 w1x[8], w1y[8], w1t[8], bb1[8];
  #pragma unroll
  for (int so = 0; so < 2; ++so)
    #pragma unroll
    for (int p = 0; p < 4; ++p) {
      int i = (2 * w + so) * 32 + quad * 8 + 2 * p;
      int idx = so * 4 + p;
      w1x[idx] = f32x2{W1[0 * HID + i], W1[0 * HID + i + 1]} * bc(K2C);
      w1y[idx] = f32x2{W1[1 * HID + i], W1[1 * HID + i + 1]} * bc(K2C);
      w1t[idx] = f32x2{W1[4 * HID + i], W1[4 * HID + i + 1]} * bc(K2C);
      bb1[idx] = f32x2{b1[i], b1[i + 1]} * bc(K2C);
    }
  // W2 A-frags for my 4 tiles (all 4 global kk) -> AGPR (64)
  Frag W2f[4][4];
  #pragma unroll
  for (int tl = 0; tl < 4; ++tl) {
    int o = (4 * w + tl) * 16 + m16;
    #pragma unroll
    for (int kk = 0; kk < 4; ++kk) {
      #pragma unroll
      for (int j = 0; j < 8; ++j)
        W2f[tl][kk].u[j] = f2bf(W2[(kk * 32 + quad * 8 + j) * HID + o] * K2C);
      asm volatile("" : "+a"(W2f[tl][kk].v));
    }
  }
  // b2 acc-init -> AGPR (16); W3 stays arch (32)
  f32x4 b2i[4];
  f32x2 w3v[4][4];
  #pragma unroll
  for (int tl = 0; tl < 4; ++tl) {
    #pragma unroll
    for (int rr = 0; rr < 4; ++rr) {
      int o = (4 * w + tl) * 16 + quad * 4 + rr;
      b2i[tl][rr] = b2[o] * K2C;
      w3v[tl][rr] = f32x2{W3[o * 2 + 0], W3[o * 2 + 1]};
    }
    asm volatile("" : "+a"(b2i[tl]));
  }
  const f32x2 b3v = f32x2{b3[0], b3[1]};

  f32x2 S = f32x2{r0[2 * s + 0], r0[2 * s + 1]};
  if (tid < 16) *(float2*)&out[(s * TT + 0) * 2] = make_float2(S.x, S.y);

  auto feval = [&](float tt, f32x2 st) -> f32x2 {
    const f32x2 sx = bc(st.x), sy = bc(st.y), tv = bc(tt);
    // ---- L1: my 2 slabs (8 tanh-pairs), keep in regs + stage to LDS ----
    uint4 own[2];
    #pragma unroll
    for (int so = 0; so < 2; ++so) {
      unsigned pd[4];
      #pragma unroll
      for (int p = 0; p < 4; ++p) {
        int idx = so * 4 + p;
        f32x2 a = pk_fma(sx, w1x[idx], bb1[idx]);
        a = pk_fma(sy, w1y[idx], a);
        a = pk_fma(tv, w1t[idx], a);
        f32x2 h = tanh_pre(a);
        pd[p] = pack2bf(h.x, h.y);
      }
      own[so] = make_uint4(pd[0], pd[1], pd[2], pd[3]);
      h1X[(2 * w + so) * 4 + quad][m16] = own[so];
    }
    __syncthreads();
    // other wave's slabs (loads overlap the first 8 MFMAs below)
    uint4 q0 = h1X[(ko + 0) * 4 + quad][m16];
    uint4 q1 = h1X[(ko + 1) * 4 + quad][m16];
    // ---- MFMAs: own slabs first (no wait), then the loaded ones ----
    Frag bv;
    f32x4 acc[4];
    bv.d[0] = own[0].x; bv.d[1] = own[0].y; bv.d[2] = own[0].z; bv.d[3] = own[0].w;
    #pragma unroll
    for (int tl = 0; tl < 4; ++tl)
      acc[tl] = __builtin_amdgcn_mfma_f32_16x16x32_bf16(
          W2f[tl][2 * w].v, bv.v, b2i[tl], 0, 0, 0);
    bv.d[0] = own[1].x; bv.d[1] = own[1].y; bv.d[2] = own[1].z; bv.d[3] = own[1].w;
    #pragma unroll
    for (int tl = 0; tl < 4; ++tl)
      acc[tl] = __builtin_amdgcn_mfma_f32_16x16x32_bf16(
          W2f[tl][2 * w + 1].v, bv.v, acc[tl], 0, 0, 0);
    bv.d[0] = q0.x; bv.d[1] = q0.y; bv.d[2] = q0.z; bv.d[3] = q0.w;
    #pragma unroll
    for (int tl = 0; tl < 4; ++tl)
      acc[tl] = __builtin_amdgcn_mfma_f32_16x16x32_bf16(
          W2f[tl][ko].v, bv.v, acc[tl], 0, 0, 0);
    bv.d[0] = q1.x; bv.d[1] = q1.y; bv.d[2] = q1.z; bv.d[3] = q1.w;
    #pragma unroll
    for (int tl = 0; tl < 4; ++tl)
      acc[tl] = __builtin_amdgcn_mfma_f32_16x16x32_bf16(
          W2f[tl][ko + 1].v, bv.v, acc[tl], 0, 0, 0);
    // ---- epilogue: 8 h2 tanh-pairs + W3 partials, 2 indep chains ----
    f32x2 vsa[2] = {bc(0.f), bc(0.f)};
    #pragma unroll
    for (int tl = 0; tl < 4; ++tl)
      #pragma unroll
      for (int p = 0; p < 2; ++p) {
        f32x2 av = f32x2{acc[tl][2 * p], acc[tl][2 * p + 1]};
        f32x2 h2 = tanh_pre(av);
        vsa[tl & 1] = pk_fma(bc(h2.x), w3v[tl][2 * p + 0], vsa[tl & 1]);
        vsa[tl & 1] = pk_fma(bc(h2.y), w3v[tl][2 * p + 1], vsa[tl & 1]);
      }
    f32x2 vs = vsa[0] + vsa[1];
    // quad reduce -> every lane holds its column's wave-partial
    float px = vs.x, py = vs.y;
    px += __shfl_xor(px, 16); py += __shfl_xor(py, 16);
    px += __shfl_xor(px, 32); py += __shfl_xor(py, 32);
    if (lane < 16) vpX[w][m16] = make_float2(px, py);
    __syncthreads();
    float2 q = vpX[1 - w][m16];
    return f32x2{px, py} + f32x2{q.x, q.y} + b3v;
  };

  #pragma unroll 1
  for (int iv = 0; iv < TT - 1; ++iv) {
    float t0 = tarr[iv], t1 = tarr[iv + 1];
    float dt = (t1 - t0) * 0.5f;
    #pragma unroll 1
    for (int ss = 0; ss < 2; ++ss) {
      float tb = (ss == 0) ? t0 : (t0 + dt);
      const f32x2 dtv = bc(dt);
      f32x2 k1 = feval(tb, S);
      f32x2 k2 = feval(tb + dt * F(1,5), pk_fma(bc(dt * F(1,5)), k1, S));
      f32x2 a3 = pk_fma(bc(F(9,40)), k2, bc(F(3,40)) * k1);
      f32x2 k3 = feval(tb + dt * F(3,10), pk_fma(dtv, a3, S));
      f32x2 a4 = pk_fma(bc(F(44,45)), k1,
                 pk_fma(bc(-F(56,15)), k2, bc(F(32,9)) * k3));
      f32x2 k4 = feval(tb + dt * F(4,5), pk_fma(dtv, a4, S));
      f32x2 a5 = pk_fma(bc(F(19372,6561)), k1,
                 pk_fma(bc(-F(25360,2187)), k2,
                 pk_fma(bc(F(64448,6561)), k3, bc(-F(212,729)) * k4)));
      f32x2 k5 = feval(tb + dt * F(8,9), pk_fma(dtv, a5, S));
      f32x2 a6 = pk_fma(bc(F(9017,3168)), k1,
                 pk_fma(bc(-F(355,33)), k2,
                 pk_fma(bc(F(46732,5247)), k3,
                 pk_fma(bc(F(49,176)), k4, bc(-F(5103,18656)) * k5))));
      f32x2 k6 = feval(tb + dt, pk_fma(dtv, a6, S));
      f32x2 fin = pk_fma(bc(F(35,384)), k1,
                  pk_fma(bc(F(500,1113)), k3,
                  pk_fma(bc(F(125,192)), k4,
                  pk_fma(bc(-F(2187,6784)), k5, bc(F(11,84)) * k6))));
      S = pk_fma(dtv, fin, S);
    }
    if (tid < 16) *(float2*)&out[(s * TT + iv + 1) * 2] = make_float2(S.x, S.y);
  }
}

extern "C" void kernel_launch(void* const* d_in, const int* in_sizes, int n_in,
                              void* d_out, int out_size, void* d_ws, size_t ws_size,
                              hipStream_t stream) {
  const float* r0 = (const float*)d_in[0];
  const float* t  = (const float*)d_in[1];
  const float* W1 = (const float*)d_in[2];
  const float* b1 = (const float*)d_in[3];
  const float* W2 = (const float*)d_in[4];
  const float* b2 = (const float*)d_in[5];
  const float* W3 = (const float*)d_in[6];
  const float* b3 = (const float*)d_in[7];
  float* out = (float*)d_out;
  const int B = in_sizes[0] / 2;        // 16384
  dim3 grid(B / 16), block(128);        // 1024 blocks x 128 threads (2 waves)
  node_kernel<<<grid, block, 0, stream>>>(r0, t, W1, b1, W2, b2, W3, b3, out);
}

// Round 11
// 193.572 us; speedup vs baseline: 2.1082x; 2.1082x over previous
//
#include <hip/hip_runtime.h>

// AugmentedNeuralODE, round 11: R10 with the scratch-demotion bug fixed.
// R10 regressed 137->367us because W2f was indexed by the RUNTIME wave id
// (W2f[tl][2*w], W2f[tl][ko]) -- dynamic indexing into a register array
// forces it to scratch (FETCH_SIZE 0.6->400 MB). Fix: store fragments in
// LOCAL slab order ll=0..3 <-> global slab g=(2w+ll)&3; w-dependence lives
// only in the preload ADDRESS. All MFMA operand indices are compile-time.
// Design (unchanged from R10): 1024 blocks x 128 thr, 2 waves share 16
// samples; out-tiles split 4/4, L1 K-slabs split 2/2; own slabs kept in
// regs + staged via LDS (2 ds_write + 2 ds_read b128 + v-exchange,
// 2 barriers/eval); W2 frags 64 AGPR + b2 16 AGPR; arch ~160 -> 2 waves/EU.
// Probe: does the quarter-rate trans stream (52% of R8's wall) co-issue
// with the other wave's full-rate/MFMA work?

#define HID 128
#define TT  8
#define F(a,b) ((float)((double)(a)/(double)(b)))
#define K2C 2.8853900817779268f   // 2*log2(e), folded into W1/b1/W2/b2

typedef __attribute__((ext_vector_type(8))) short bf16x8;
typedef __attribute__((ext_vector_type(4))) float f32x4;
typedef __attribute__((ext_vector_type(2))) float f32x2;

union Frag { bf16x8 v; unsigned short u[8]; unsigned int d[4]; };

__device__ __forceinline__ f32x2 bc(float s) { return f32x2{s, s}; }
__device__ __forceinline__ f32x2 pk_fma(f32x2 a, f32x2 b, f32x2 c) {
#if __has_builtin(__builtin_elementwise_fma)
  return __builtin_elementwise_fma(a, b, c);
#else
  return a * b + c;
#endif
}
__device__ __forceinline__ float exp2_fast(float x) {
#if __has_builtin(__builtin_amdgcn_exp2f)
  return __builtin_amdgcn_exp2f(x);
#else
  return __builtin_exp2f(x);
#endif
}
__device__ __forceinline__ unsigned short f2bf(float f) {
  unsigned u = __builtin_bit_cast(unsigned, f);
  u += 0x7FFFu + ((u >> 16) & 1u);          // RNE
  return (unsigned short)(u >> 16);
}
__device__ __forceinline__ unsigned pack2bf(float a, float b) {
  unsigned ua = __builtin_bit_cast(unsigned, a);
  unsigned ub = __builtin_bit_cast(unsigned, b);
  ua += 0x7FFFu + ((ua >> 16) & 1u);
  ub += 0x7FFFu + ((ub >> 16) & 1u);
  return __builtin_amdgcn_perm(ub, ua, 0x07060302u);
}
// u pre-scaled by 2*log2(e): tanh(x) = 1 - 2/(exp2(u)+1)
__device__ __forceinline__ f32x2 tanh_pre(f32x2 u) {
  f32x2 e;
  e.x = exp2_fast(u.x);
  e.y = exp2_fast(u.y);
  f32x2 d = e + bc(1.0f);
  f32x2 r;
  r.x = __builtin_amdgcn_rcpf(d.x);
  r.y = __builtin_amdgcn_rcpf(d.y);
  return pk_fma(bc(-2.0f), r, bc(1.0f));
}

__global__ __launch_bounds__(128, 2) void node_kernel(
    const float* __restrict__ r0, const float* __restrict__ tarr,
    const float* __restrict__ W1, const float* __restrict__ b1,
    const float* __restrict__ W2, const float* __restrict__ b2,
    const float* __restrict__ W3, const float* __restrict__ b3,
    float* __restrict__ out)
{
  __shared__ uint4  h1X[16][16];   // [g*4+quad][m16], 16B each; 4 KB
  __shared__ float2 vpX[2][16];    // per-wave partial velocity; 256 B

  const int tid  = (int)threadIdx.x;
  const int lane = tid & 63;
  const int w    = __builtin_amdgcn_readfirstlane(tid >> 6); // 0 or 1
  const int quad = lane >> 4;
  const int m16  = lane & 15;
  const int s    = (int)blockIdx.x * 16 + m16;
  const int ko   = (1 - w) * 2;        // other wave's first global slab

  // ---- preloads, K2-folded ----
  // L1 coeffs for my 2 global slabs {2w, 2w+1}: units i = (2w+so)*32+quad*8+j
  f32x2 w1x[8], w1y[8], w1t[8], bb1[8];
  #pragma unroll
  for (int so = 0; so < 2; ++so)
    #pragma unroll
    for (int p = 0; p < 4; ++p) {
      int i = (2 * w + so) * 32 + quad * 8 + 2 * p;
      int idx = so * 4 + p;
      w1x[idx] = f32x2{W1[0 * HID + i], W1[0 * HID + i + 1]} * bc(K2C);
      w1y[idx] = f32x2{W1[1 * HID + i], W1[1 * HID + i + 1]} * bc(K2C);
      w1t[idx] = f32x2{W1[4 * HID + i], W1[4 * HID + i + 1]} * bc(K2C);
      bb1[idx] = f32x2{b1[i], b1[i + 1]} * bc(K2C);
    }
  // W2 A-frags in LOCAL slab order: W2f[tl][ll] <- global slab g=(2w+ll)&3.
  // All consuming indices are compile-time -> stays register-allocated.
  Frag W2f[4][4];
  #pragma unroll
  for (int tl = 0; tl < 4; ++tl) {
    int o = (4 * w + tl) * 16 + m16;
    #pragma unroll
    for (int ll = 0; ll < 4; ++ll) {
      int g = (2 * w + ll) & 3;        // runtime only in the LOAD address
      #pragma unroll
      for (int j = 0; j < 8; ++j)
        W2f[tl][ll].u[j] = f2bf(W2[(g * 32 + quad * 8 + j) * HID + o] * K2C);
      asm volatile("" : "+a"(W2f[tl][ll].v));   // park in AGPR (MFMA A-src)
    }
  }
  // b2 acc-init -> AGPR (16); W3 arch (32)
  f32x4 b2i[4];
  f32x2 w3v[4][4];
  #pragma unroll
  for (int tl = 0; tl < 4; ++tl) {
    #pragma unroll
    for (int rr = 0; rr < 4; ++rr) {
      int o = (4 * w + tl) * 16 + quad * 4 + rr;
      b2i[tl][rr] = b2[o] * K2C;
      w3v[tl][rr] = f32x2{W3[o * 2 + 0], W3[o * 2 + 1]};
    }
    asm volatile("" : "+a"(b2i[tl]));
  }
  const f32x2 b3v = f32x2{b3[0], b3[1]};

  f32x2 S = f32x2{r0[2 * s + 0], r0[2 * s + 1]};
  if (tid < 16) *(float2*)&out[(s * TT + 0) * 2] = make_float2(S.x, S.y);

  auto feval = [&](float tt, f32x2 st) -> f32x2 {
    const f32x2 sx = bc(st.x), sy = bc(st.y), tv = bc(tt);
    // ---- L1: my 2 slabs (8 tanh-pairs), keep in regs + stage to LDS ----
    uint4 own0, own1;
    {
      unsigned pd[8];
      #pragma unroll
      for (int idx = 0; idx < 8; ++idx) {
        f32x2 a = pk_fma(sx, w1x[idx], bb1[idx]);
        a = pk_fma(sy, w1y[idx], a);
        a = pk_fma(tv, w1t[idx], a);
        f32x2 h = tanh_pre(a);
        pd[idx] = pack2bf(h.x, h.y);
      }
      own0 = make_uint4(pd[0], pd[1], pd[2], pd[3]);
      own1 = make_uint4(pd[4], pd[5], pd[6], pd[7]);
      h1X[(2 * w + 0) * 4 + quad][m16] = own0;
      h1X[(2 * w + 1) * 4 + quad][m16] = own1;
    }
    __syncthreads();
    // other wave's slabs (loads overlap the first 8 MFMAs below)
    uint4 q0 = h1X[(ko + 0) * 4 + quad][m16];
    uint4 q1 = h1X[(ko + 1) * 4 + quad][m16];
    // ---- MFMAs: local slab order ll=0,1 (own, no wait), 2,3 (loaded) ----
    Frag bv;
    f32x4 acc[4];
    bv.d[0] = own0.x; bv.d[1] = own0.y; bv.d[2] = own0.z; bv.d[3] = own0.w;
    #pragma unroll
    for (int tl = 0; tl < 4; ++tl)
      acc[tl] = __builtin_amdgcn_mfma_f32_16x16x32_bf16(
          W2f[tl][0].v, bv.v, b2i[tl], 0, 0, 0);
    bv.d[0] = own1.x; bv.d[1] = own1.y; bv.d[2] = own1.z; bv.d[3] = own1.w;
    #pragma unroll
    for (int tl = 0; tl < 4; ++tl)
      acc[tl] = __builtin_amdgcn_mfma_f32_16x16x32_bf16(
          W2f[tl][1].v, bv.v, acc[tl], 0, 0, 0);
    bv.d[0] = q0.x; bv.d[1] = q0.y; bv.d[2] = q0.z; bv.d[3] = q0.w;
    #pragma unroll
    for (int tl = 0; tl < 4; ++tl)
      acc[tl] = __builtin_amdgcn_mfma_f32_16x16x32_bf16(
          W2f[tl][2].v, bv.v, acc[tl], 0, 0, 0);
    bv.d[0] = q1.x; bv.d[1] = q1.y; bv.d[2] = q1.z; bv.d[3] = q1.w;
    #pragma unroll
    for (int tl = 0; tl < 4; ++tl)
      acc[tl] = __builtin_amdgcn_mfma_f32_16x16x32_bf16(
          W2f[tl][3].v, bv.v, acc[tl], 0, 0, 0);
    // ---- epilogue: 8 h2 tanh-pairs + W3 partials, 2 indep chains ----
    f32x2 vsa[2] = {bc(0.f), bc(0.f)};
    #pragma unroll
    for (int tl = 0; tl < 4; ++tl)
      #pragma unroll
      for (int p = 0; p < 2; ++p) {
        f32x2 av = f32x2{acc[tl][2 * p], acc[tl][2 * p + 1]};
        f32x2 h2 = tanh_pre(av);
        vsa[tl & 1] = pk_fma(bc(h2.x), w3v[tl][2 * p + 0], vsa[tl & 1]);
        vsa[tl & 1] = pk_fma(bc(h2.y), w3v[tl][2 * p + 1], vsa[tl & 1]);
      }
    f32x2 vs = vsa[0] + vsa[1];
    // quad reduce -> every lane holds its column's wave-partial
    float px = vs.x, py = vs.y;
    px += __shfl_xor(px, 16); py += __shfl_xor(py, 16);
    px += __shfl_xor(px, 32); py += __shfl_xor(py, 32);
    if (lane < 16) vpX[w][m16] = make_float2(px, py);
    __syncthreads();
    float2 q = vpX[1 - w][m16];
    return f32x2{px, py} + f32x2{q.x, q.y} + b3v;
  };

  #pragma unroll 1
  for (int iv = 0; iv < TT - 1; ++iv) {
    float t0 = tarr[iv], t1 = tarr[iv + 1];
    float dt = (t1 - t0) * 0.5f;
    #pragma unroll 1
    for (int ss = 0; ss < 2; ++ss) {
      float tb = (ss == 0) ? t0 : (t0 + dt);
      const f32x2 dtv = bc(dt);
      f32x2 k1 = feval(tb, S);
      f32x2 k2 = feval(tb + dt * F(1,5), pk_fma(bc(dt * F(1,5)), k1, S));
      f32x2 a3 = pk_fma(bc(F(9,40)), k2, bc(F(3,40)) * k1);
      f32x2 k3 = feval(tb + dt * F(3,10), pk_fma(dtv, a3, S));
      f32x2 a4 = pk_fma(bc(F(44,45)), k1,
                 pk_fma(bc(-F(56,15)), k2, bc(F(32,9)) * k3));
      f32x2 k4 = feval(tb + dt * F(4,5), pk_fma(dtv, a4, S));
      f32x2 a5 = pk_fma(bc(F(19372,6561)), k1,
                 pk_fma(bc(-F(25360,2187)), k2,
                 pk_fma(bc(F(64448,6561)), k3, bc(-F(212,729)) * k4)));
      f32x2 k5 = feval(tb + dt * F(8,9), pk_fma(dtv, a5, S));
      f32x2 a6 = pk_fma(bc(F(9017,3168)), k1,
                 pk_fma(bc(-F(355,33)), k2,
                 pk_fma(bc(F(46732,5247)), k3,
                 pk_fma(bc(F(49,176)), k4, bc(-F(5103,18656)) * k5))));
      f32x2 k6 = feval(tb + dt, pk_fma(dtv, a6, S));
      f32x2 fin = pk_fma(bc(F(35,384)), k1,
                  pk_fma(bc(F(500,1113)), k3,
                  pk_fma(bc(F(125,192)), k4,
                  pk_fma(bc(-F(2187,6784)), k5, bc(F(11,84)) * k6))));
      S = pk_fma(dtv, fin, S);
    }
    if (tid < 16) *(float2*)&out[(s * TT + iv + 1) * 2] = make_float2(S.x, S.y);
  }
}

extern "C" void kernel_launch(void* const* d_in, const int* in_sizes, int n_in,
                              void* d_out, int out_size, void* d_ws, size_t ws_size,
                              hipStream_t stream) {
  const float* r0 = (const float*)d_in[0];
  const float* t  = (const float*)d_in[1];
  const float* W1 = (const float*)d_in[2];
  const float* b1 = (const float*)d_in[3];
  const float* W2 = (const float*)d_in[4];
  const float* b2 = (const float*)d_in[5];
  const float* W3 = (const float*)d_in[6];
  const float* b3 = (const float*)d_in[7];
  float* out = (float*)d_out;
  const int B = in_sizes[0] / 2;        // 16384
  dim3 grid(B / 16), block(128);        // 1024 blocks x 128 threads (2 waves)
  node_kernel<<<grid, block, 0, stream>>>(r0, t, W1, b1, W2, b2, W3, b3, out);
}

// Round 12
// 182.504 us; speedup vs baseline: 2.2360x; 1.0606x over previous
//
#include <hip/hip_runtime.h>

// AugmentedNeuralODE, round 12: R8 + issue-cycle harvest.
// Settled model (R9 ILP-neutral, R11 2-wave-neutral): SIMD is issue-port
// bound; trans ops hold the port 8 cyc each and cannot be overlapped by a
// second wave. Wall ~= total issue cycles (~1957/eval at R8). All tanh
// alternatives (poly/Pade/LUT/doubling) cost the same ~34 cyc/pair -> cut
// what's cuttable:
//  1. h1 pack via v_cvt_pk_bf16_f32 (1 op vs 3), has_builtin-guarded.
//  2. combined pair-rcp: r=rcp(d.x*d.y); q={r*d.y, r*d.x} -- 1 trans/pair
//     instead of 2. Overflow-safe: K2-folded preacts <=~47 -> d.x*d.y<2^95.
//  3. epilogue folds 1-2q into W3: vs = sum(w3) - sum(2*w3)q (per-lane
//     sum(w3) precomputed) -- drops the h2=1-2q op.
// Else identical to R8: 1024x64, 1 wave/SIMD, W2/b2 in AGPRs, zero LDS.

#define HID 128
#define TT  8
#define F(a,b) ((float)((double)(a)/(double)(b)))
#define K2C 2.8853900817779268f   // 2*log2(e), folded into W1/b1/W2/b2

typedef __attribute__((ext_vector_type(8))) short bf16x8;
typedef __attribute__((ext_vector_type(4))) float f32x4;
typedef __attribute__((ext_vector_type(2))) float f32x2;

union Frag { bf16x8 v; unsigned short u[8]; unsigned int d[4]; };

__device__ __forceinline__ f32x2 bc(float s) { return f32x2{s, s}; }
__device__ __forceinline__ f32x2 pk_fma(f32x2 a, f32x2 b, f32x2 c) {
#if __has_builtin(__builtin_elementwise_fma)
  return __builtin_elementwise_fma(a, b, c);
#else
  return a * b + c;
#endif
}
__device__ __forceinline__ float exp2_fast(float x) {
#if __has_builtin(__builtin_amdgcn_exp2f)
  return __builtin_amdgcn_exp2f(x);
#else
  return __builtin_exp2f(x);
#endif
}
__device__ __forceinline__ unsigned short f2bf(float f) {
  unsigned u = __builtin_bit_cast(unsigned, f);
  u += 0x7FFFu + ((u >> 16) & 1u);          // RNE
  return (unsigned short)(u >> 16);
}
// packed bf16 pair: lo = a, hi = b
__device__ __forceinline__ unsigned pack2bf(float a, float b) {
#if __has_builtin(__builtin_amdgcn_cvt_pk_bf16_f32)
  auto pk = __builtin_amdgcn_cvt_pk_bf16_f32(a, b);   // v_cvt_pk_bf16_f32
  return __builtin_bit_cast(unsigned, pk);
#else
  unsigned ua = __builtin_bit_cast(unsigned, a);
  unsigned ub = __builtin_bit_cast(unsigned, b);
  ua += 0x7FFFu + ((ua >> 16) & 1u);
  ub += 0x7FFFu + ((ub >> 16) & 1u);
  return __builtin_amdgcn_perm(ub, ua, 0x07060302u);
#endif
}
// u pre-scaled by 2*log2(e). Returns q = 1/(exp2(u)+1) per element, using
// ONE rcp for the pair: 1/dx = rcp(dx*dy)*dy. tanh(x) = 1 - 2q.
__device__ __forceinline__ f32x2 sig_q(f32x2 u) {
  f32x2 e;
  e.x = exp2_fast(u.x);
  e.y = exp2_fast(u.y);
  f32x2 d = e + bc(1.0f);
  float dd = d.x * d.y;
  float r = __builtin_amdgcn_rcpf(dd);
  f32x2 q;
  q.x = r * d.y;
  q.y = r * d.x;
  return q;
}

__global__ __launch_bounds__(64, 1) void node_kernel(
    const float* __restrict__ r0, const float* __restrict__ tarr,
    const float* __restrict__ W1, const float* __restrict__ b1,
    const float* __restrict__ W2, const float* __restrict__ b2,
    const float* __restrict__ W3, const float* __restrict__ b3,
    float* __restrict__ out)
{
  const int lane = (int)(threadIdx.x & 63u);
  const int quad = lane >> 4;          // 0..3
  const int m16  = lane & 15;          // my sample (column)
  const int s    = (int)blockIdx.x * 16 + m16;

  // ---- one-time preloads, all K2-folded ----
  // W1 for my 32 units k = kk*32 + quad*8 + j (16 pairs) -- arch VGPRs (128)
  f32x2 w1x[16], w1y[16], w1t[16], bb1[16];
  #pragma unroll
  for (int kk = 0; kk < 4; ++kk)
    #pragma unroll
    for (int p = 0; p < 4; ++p) {
      int i = kk * 32 + quad * 8 + 2 * p;
      int idx = kk * 4 + p;
      w1x[idx] = f32x2{W1[0 * HID + i], W1[0 * HID + i + 1]} * bc(K2C);
      w1y[idx] = f32x2{W1[1 * HID + i], W1[1 * HID + i + 1]} * bc(K2C);
      w1t[idx] = f32x2{W1[4 * HID + i], W1[4 * HID + i + 1]} * bc(K2C);
      bb1[idx] = f32x2{b1[i], b1[i + 1]} * bc(K2C);
    }
  // W2 A-frags for ALL 8 out-tiles -> pinned into AGPRs (128 regs)
  Frag W2f[8][4];
  #pragma unroll
  for (int t = 0; t < 8; ++t) {
    int o = t * 16 + m16;
    #pragma unroll
    for (int kk = 0; kk < 4; ++kk) {
      #pragma unroll
      for (int j = 0; j < 8; ++j)
        W2f[t][kk].u[j] = f2bf(W2[(kk * 32 + quad * 8 + j) * HID + o] * K2C);
      asm volatile("" : "+a"(W2f[t][kk].v));   // park in AGPR (MFMA A-src)
    }
  }
  // acc-init = b2*K2 -> AGPR (32, MFMA C-src); W3 as -2*w3 pairs + w3-sum
  f32x4 b2i[8];
  f32x2 w3n2[8][4];                     // {-2*w3x, -2*w3y} per h2 row
  f32x2 w3s = bc(0.f);                  // sum of w3 over this lane's rows
  #pragma unroll
  for (int t = 0; t < 8; ++t) {
    #pragma unroll
    for (int rr = 0; rr < 4; ++rr) {
      int o = t * 16 + quad * 4 + rr;
      b2i[t][rr] = b2[o] * K2C;
      f32x2 w3 = f32x2{W3[o * 2 + 0], W3[o * 2 + 1]};
      w3s += w3;
      w3n2[t][rr] = w3 * bc(-2.f);
    }
    asm volatile("" : "+a"(b2i[t]));
  }
  const f32x2 b3v = f32x2{b3[0], b3[1]};

  f32x2 S = f32x2{r0[2 * s + 0], r0[2 * s + 1]};
  if (lane < 16) *(float2*)&out[(s * TT + 0) * 2] = make_float2(S.x, S.y);

  auto feval = [&](float tt, f32x2 st) -> f32x2 {
    const f32x2 sx = bc(st.x), sy = bc(st.y), tv = bc(tt);
    // ---- interleaved: per K-slab, 4 tanh-pairs -> B-frag -> 8 MFMAs ----
    f32x4 acc[8];
    #pragma unroll
    for (int kk = 0; kk < 4; ++kk) {
      unsigned pd[4];
      #pragma unroll
      for (int p = 0; p < 4; ++p) {
        int idx = kk * 4 + p;
        f32x2 a = pk_fma(sx, w1x[idx], bb1[idx]);
        a = pk_fma(sy, w1y[idx], a);
        a = pk_fma(tv, w1t[idx], a);
        f32x2 q = sig_q(a);
        f32x2 h = pk_fma(bc(-2.0f), q, bc(1.0f));   // tanh
        pd[p] = pack2bf(h.x, h.y);
      }
      Frag bv;
      bv.d[0] = pd[0]; bv.d[1] = pd[1]; bv.d[2] = pd[2]; bv.d[3] = pd[3];
      if (kk == 0) {
        #pragma unroll
        for (int t = 0; t < 8; ++t)
          acc[t] = __builtin_amdgcn_mfma_f32_16x16x32_bf16(
              W2f[t][0].v, bv.v, b2i[t], 0, 0, 0);
      } else {
        #pragma unroll
        for (int t = 0; t < 8; ++t)
          acc[t] = __builtin_amdgcn_mfma_f32_16x16x32_bf16(
              W2f[t][kk].v, bv.v, acc[t], 0, 0, 0);
      }
    }
    // ---- epilogue: vs = sum(w3) + sum((-2*w3) * q)  (1-2q fold) ----
    f32x2 vsa[2] = {w3s, bc(0.f)};
    #pragma unroll
    for (int t = 0; t < 8; ++t)
      #pragma unroll
      for (int p = 0; p < 2; ++p) {
        f32x2 av = f32x2{acc[t][2 * p], acc[t][2 * p + 1]};
        f32x2 q = sig_q(av);
        vsa[t & 1] = pk_fma(bc(q.x), w3n2[t][2 * p + 0], vsa[t & 1]);
        vsa[t & 1] = pk_fma(bc(q.y), w3n2[t][2 * p + 1], vsa[t & 1]);
      }
    f32x2 vs = vsa[0] + vsa[1];
    // cross-quad reduce (sample m16 partials live at lanes m16+16q)
    float px = vs.x, py = vs.y;
    px += __shfl_xor(px, 16); py += __shfl_xor(py, 16);
    px += __shfl_xor(px, 32); py += __shfl_xor(py, 32);
    return f32x2{px, py} + b3v;
  };

  #pragma unroll 1
  for (int iv = 0; iv < TT - 1; ++iv) {
    float t0 = tarr[iv], t1 = tarr[iv + 1];
    float dt = (t1 - t0) * 0.5f;
    #pragma unroll 1
    for (int ss = 0; ss < 2; ++ss) {
      float tb = (ss == 0) ? t0 : (t0 + dt);
      const f32x2 dtv = bc(dt);
      f32x2 k1 = feval(tb, S);
      f32x2 k2 = feval(tb + dt * F(1,5), pk_fma(bc(dt * F(1,5)), k1, S));
      f32x2 a3 = pk_fma(bc(F(9,40)), k2, bc(F(3,40)) * k1);
      f32x2 k3 = feval(tb + dt * F(3,10), pk_fma(dtv, a3, S));
      f32x2 a4 = pk_fma(bc(F(44,45)), k1,
                 pk_fma(bc(-F(56,15)), k2, bc(F(32,9)) * k3));
      f32x2 k4 = feval(tb + dt * F(4,5), pk_fma(dtv, a4, S));
      f32x2 a5 = pk_fma(bc(F(19372,6561)), k1,
                 pk_fma(bc(-F(25360,2187)), k2,
                 pk_fma(bc(F(64448,6561)), k3, bc(-F(212,729)) * k4)));
      f32x2 k5 = feval(tb + dt * F(8,9), pk_fma(dtv, a5, S));
      f32x2 a6 = pk_fma(bc(F(9017,3168)), k1,
                 pk_fma(bc(-F(355,33)), k2,
                 pk_fma(bc(F(46732,5247)), k3,
                 pk_fma(bc(F(49,176)), k4, bc(-F(5103,18656)) * k5))));
      f32x2 k6 = feval(tb + dt, pk_fma(dtv, a6, S));
      f32x2 fin = pk_fma(bc(F(35,384)), k1,
                  pk_fma(bc(F(500,1113)), k3,
                  pk_fma(bc(F(125,192)), k4,
                  pk_fma(bc(-F(2187,6784)), k5, bc(F(11,84)) * k6))));
      S = pk_fma(dtv, fin, S);
    }
    if (lane < 16) *(float2*)&out[(s * TT + iv + 1) * 2] = make_float2(S.x, S.y);
  }
}

extern "C" void kernel_launch(void* const* d_in, const int* in_sizes, int n_in,
                              void* d_out, int out_size, void* d_ws, size_t ws_size,
                              hipStream_t stream) {
  const float* r0 = (const float*)d_in[0];
  const float* t  = (const float*)d_in[1];
  const float* W1 = (const float*)d_in[2];
  const float* b1 = (const float*)d_in[3];
  const float* W2 = (const float*)d_in[4];
  const float* b2 = (const float*)d_in[5];
  const float* W3 = (const float*)d_in[6];
  const float* b3 = (const float*)d_in[7];
  float* out = (float*)d_out;
  const int B = in_sizes[0] / 2;        // 16384
  dim3 grid(B / 16), block(64);         // 1024 blocks x 64 threads (1 wave)
  node_kernel<<<grid, block, 0, stream>>>(r0, t, W1, b1, W2, b2, W3, b3, out);
}

// Round 13
// 177.764 us; speedup vs baseline: 2.2956x; 1.0267x over previous
//
#include <hip/hip_runtime.h>

// AugmentedNeuralODE, round 13: revert R12's shared-rcp (latency poison),
// keep its two clean issue cuts. == R8 structure exactly (1024x64, 1 wave/
// SIMD, W2+b2 in AGPRs, zero LDS/barriers, interleaved L1->MFMA per K-slab,
// separate rcp per tanh element -> independent x/y chains) plus:
//  1. h1 bf16 pack via v_cvt_pk_bf16_f32 (1 op vs 3; RNE semantics match
//     the manual pack -- verified by R12's identical absmax).
//  2. epilogue folds h2=1-2q into W3: vs = sum(w3) + sum((-2*w3)*q);
//     q -> pk_fma directly, chain length unchanged vs R8.
// Model (fits R3-R12): wall ~= per-wave issue-cycle sum (trans=8, pk=2);
// only chain-neutral op removal moves the wall.

#define HID 128
#define TT  8
#define F(a,b) ((float)((double)(a)/(double)(b)))
#define K2C 2.8853900817779268f   // 2*log2(e), folded into W1/b1/W2/b2

typedef __attribute__((ext_vector_type(8))) short bf16x8;
typedef __attribute__((ext_vector_type(4))) float f32x4;
typedef __attribute__((ext_vector_type(2))) float f32x2;

union Frag { bf16x8 v; unsigned short u[8]; unsigned int d[4]; };

__device__ __forceinline__ f32x2 bc(float s) { return f32x2{s, s}; }
__device__ __forceinline__ f32x2 pk_fma(f32x2 a, f32x2 b, f32x2 c) {
#if __has_builtin(__builtin_elementwise_fma)
  return __builtin_elementwise_fma(a, b, c);
#else
  return a * b + c;
#endif
}
__device__ __forceinline__ float exp2_fast(float x) {
#if __has_builtin(__builtin_amdgcn_exp2f)
  return __builtin_amdgcn_exp2f(x);
#else
  return __builtin_exp2f(x);
#endif
}
__device__ __forceinline__ unsigned short f2bf(float f) {
  unsigned u = __builtin_bit_cast(unsigned, f);
  u += 0x7FFFu + ((u >> 16) & 1u);          // RNE
  return (unsigned short)(u >> 16);
}
// packed bf16 pair: lo = a, hi = b
__device__ __forceinline__ unsigned pack2bf(float a, float b) {
#if __has_builtin(__builtin_amdgcn_cvt_pk_bf16_f32)
  auto pk = __builtin_amdgcn_cvt_pk_bf16_f32(a, b);   // v_cvt_pk_bf16_f32
  return __builtin_bit_cast(unsigned, pk);
#else
  unsigned ua = __builtin_bit_cast(unsigned, a);
  unsigned ub = __builtin_bit_cast(unsigned, b);
  ua += 0x7FFFu + ((ua >> 16) & 1u);
  ub += 0x7FFFu + ((ub >> 16) & 1u);
  return __builtin_amdgcn_perm(ub, ua, 0x07060302u);
#endif
}
// u pre-scaled by 2*log2(e): q = 1/(exp2(u)+1), SEPARATE rcp per element
// (independent x/y chains -- the R12 shared-rcp coupling cost +39us).
__device__ __forceinline__ f32x2 sig_q(f32x2 u) {
  f32x2 e;
  e.x = exp2_fast(u.x);
  e.y = exp2_fast(u.y);
  f32x2 d = e + bc(1.0f);
  f32x2 q;
  q.x = __builtin_amdgcn_rcpf(d.x);
  q.y = __builtin_amdgcn_rcpf(d.y);
  return q;
}
// tanh(x) = 1 - 2q
__device__ __forceinline__ f32x2 tanh_pre(f32x2 u) {
  return pk_fma(bc(-2.0f), sig_q(u), bc(1.0f));
}

__global__ __launch_bounds__(64, 1) void node_kernel(
    const float* __restrict__ r0, const float* __restrict__ tarr,
    const float* __restrict__ W1, const float* __restrict__ b1,
    const float* __restrict__ W2, const float* __restrict__ b2,
    const float* __restrict__ W3, const float* __restrict__ b3,
    float* __restrict__ out)
{
  const int lane = (int)(threadIdx.x & 63u);
  const int quad = lane >> 4;          // 0..3
  const int m16  = lane & 15;          // my sample (column)
  const int s    = (int)blockIdx.x * 16 + m16;

  // ---- one-time preloads, all K2-folded ----
  // W1 for my 32 units k = kk*32 + quad*8 + j (16 pairs) -- arch VGPRs (128)
  f32x2 w1x[16], w1y[16], w1t[16], bb1[16];
  #pragma unroll
  for (int kk = 0; kk < 4; ++kk)
    #pragma unroll
    for (int p = 0; p < 4; ++p) {
      int i = kk * 32 + quad * 8 + 2 * p;
      int idx = kk * 4 + p;
      w1x[idx] = f32x2{W1[0 * HID + i], W1[0 * HID + i + 1]} * bc(K2C);
      w1y[idx] = f32x2{W1[1 * HID + i], W1[1 * HID + i + 1]} * bc(K2C);
      w1t[idx] = f32x2{W1[4 * HID + i], W1[4 * HID + i + 1]} * bc(K2C);
      bb1[idx] = f32x2{b1[i], b1[i + 1]} * bc(K2C);
    }
  // W2 A-frags for ALL 8 out-tiles -> pinned into AGPRs (128 regs)
  Frag W2f[8][4];
  #pragma unroll
  for (int t = 0; t < 8; ++t) {
    int o = t * 16 + m16;
    #pragma unroll
    for (int kk = 0; kk < 4; ++kk) {
      #pragma unroll
      for (int j = 0; j < 8; ++j)
        W2f[t][kk].u[j] = f2bf(W2[(kk * 32 + quad * 8 + j) * HID + o] * K2C);
      asm volatile("" : "+a"(W2f[t][kk].v));   // park in AGPR (MFMA A-src)
    }
  }
  // acc-init = b2*K2 -> AGPR (32, MFMA C-src); W3 as -2*w3 pairs + w3-sum
  f32x4 b2i[8];
  f32x2 w3n2[8][4];                     // {-2*w3x, -2*w3y} per h2 row
  f32x2 w3s = bc(0.f);                  // sum of w3 over this lane's rows
  #pragma unroll
  for (int t = 0; t < 8; ++t) {
    #pragma unroll
    for (int rr = 0; rr < 4; ++rr) {
      int o = t * 16 + quad * 4 + rr;
      b2i[t][rr] = b2[o] * K2C;
      f32x2 w3 = f32x2{W3[o * 2 + 0], W3[o * 2 + 1]};
      w3s += w3;
      w3n2[t][rr] = w3 * bc(-2.f);
    }
    asm volatile("" : "+a"(b2i[t]));
  }
  const f32x2 b3v = f32x2{b3[0], b3[1]};

  f32x2 S = f32x2{r0[2 * s + 0], r0[2 * s + 1]};
  if (lane < 16) *(float2*)&out[(s * TT + 0) * 2] = make_float2(S.x, S.y);

  auto feval = [&](float tt, f32x2 st) -> f32x2 {
    const f32x2 sx = bc(st.x), sy = bc(st.y), tv = bc(tt);
    // ---- interleaved: per K-slab, 4 tanh-pairs -> B-frag -> 8 MFMAs ----
    f32x4 acc[8];
    #pragma unroll
    for (int kk = 0; kk < 4; ++kk) {
      unsigned pd[4];
      #pragma unroll
      for (int p = 0; p < 4; ++p) {
        int idx = kk * 4 + p;
        f32x2 a = pk_fma(sx, w1x[idx], bb1[idx]);
        a = pk_fma(sy, w1y[idx], a);
        a = pk_fma(tv, w1t[idx], a);
        f32x2 h = tanh_pre(a);
        pd[p] = pack2bf(h.x, h.y);
      }
      Frag bv;
      bv.d[0] = pd[0]; bv.d[1] = pd[1]; bv.d[2] = pd[2]; bv.d[3] = pd[3];
      if (kk == 0) {
        #pragma unroll
        for (int t = 0; t < 8; ++t)
          acc[t] = __builtin_amdgcn_mfma_f32_16x16x32_bf16(
              W2f[t][0].v, bv.v, b2i[t], 0, 0, 0);
      } else {
        #pragma unroll
        for (int t = 0; t < 8; ++t)
          acc[t] = __builtin_amdgcn_mfma_f32_16x16x32_bf16(
              W2f[t][kk].v, bv.v, acc[t], 0, 0, 0);
      }
    }
    // ---- epilogue: vs = sum(w3) + sum((-2*w3) * q), separate rcps ----
    f32x2 vsa[2] = {w3s, bc(0.f)};
    #pragma unroll
    for (int t = 0; t < 8; ++t)
      #pragma unroll
      for (int p = 0; p < 2; ++p) {
        f32x2 av = f32x2{acc[t][2 * p], acc[t][2 * p + 1]};
        f32x2 q = sig_q(av);
        vsa[t & 1] = pk_fma(bc(q.x), w3n2[t][2 * p + 0], vsa[t & 1]);
        vsa[t & 1] = pk_fma(bc(q.y), w3n2[t][2 * p + 1], vsa[t & 1]);
      }
    f32x2 vs = vsa[0] + vsa[1];
    // cross-quad reduce (sample m16 partials live at lanes m16+16q)
    float px = vs.x, py = vs.y;
    px += __shfl_xor(px, 16); py += __shfl_xor(py, 16);
    px += __shfl_xor(px, 32); py += __shfl_xor(py, 32);
    return f32x2{px, py} + b3v;
  };

  #pragma unroll 1
  for (int iv = 0; iv < TT - 1; ++iv) {
    float t0 = tarr[iv], t1 = tarr[iv + 1];
    float dt = (t1 - t0) * 0.5f;
    #pragma unroll 1
    for (int ss = 0; ss < 2; ++ss) {
      float tb = (ss == 0) ? t0 : (t0 + dt);
      const f32x2 dtv = bc(dt);
      f32x2 k1 = feval(tb, S);
      f32x2 k2 = feval(tb + dt * F(1,5), pk_fma(bc(dt * F(1,5)), k1, S));
      f32x2 a3 = pk_fma(bc(F(9,40)), k2, bc(F(3,40)) * k1);
      f32x2 k3 = feval(tb + dt * F(3,10), pk_fma(dtv, a3, S));
      f32x2 a4 = pk_fma(bc(F(44,45)), k1,
                 pk_fma(bc(-F(56,15)), k2, bc(F(32,9)) * k3));
      f32x2 k4 = feval(tb + dt * F(4,5), pk_fma(dtv, a4, S));
      f32x2 a5 = pk_fma(bc(F(19372,6561)), k1,
                 pk_fma(bc(-F(25360,2187)), k2,
                 pk_fma(bc(F(64448,6561)), k3, bc(-F(212,729)) * k4)));
      f32x2 k5 = feval(tb + dt * F(8,9), pk_fma(dtv, a5, S));
      f32x2 a6 = pk_fma(bc(F(9017,3168)), k1,
                 pk_fma(bc(-F(355,33)), k2,
                 pk_fma(bc(F(46732,5247)), k3,
                 pk_fma(bc(F(49,176)), k4, bc(-F(5103,18656)) * k5))));
      f32x2 k6 = feval(tb + dt, pk_fma(dtv, a6, S));
      f32x2 fin = pk_fma(bc(F(35,384)), k1,
                  pk_fma(bc(F(500,1113)), k3,
                  pk_fma(bc(F(125,192)), k4,
                  pk_fma(bc(-F(2187,6784)), k5, bc(F(11,84)) * k6))));
      S = pk_fma(dtv, fin, S);
    }
    if (lane < 16) *(float2*)&out[(s * TT + iv + 1) * 2] = make_float2(S.x, S.y);
  }
}

extern "C" void kernel_launch(void* const* d_in, const int* in_sizes, int n_in,
                              void* d_out, int out_size, void* d_ws, size_t ws_size,
                              hipStream_t stream) {
  const float* r0 = (const float*)d_in[0];
  const float* t  = (const float*)d_in[1];
  const float* W1 = (const float*)d_in[2];
  const float* b1 = (const float*)d_in[3];
  const float* W2 = (const float*)d_in[4];
  const float* b2 = (const float*)d_in[5];
  const float* W3 = (const float*)d_in[6];
  const float* b3 = (const float*)d_in[7];
  float* out = (float*)d_out;
  const int B = in_sizes[0] / 2;        // 16384
  dim3 grid(B / 16), block(64);         // 1024 blocks x 64 threads (1 wave)
  node_kernel<<<grid, block, 0, stream>>>(r0, t, W1, b1, W2, b2, W3, b3, out);
}